// Round 6
// baseline (627.062 us; speedup 1.0000x reference)
//
#include <hip/hip_runtime.h>
#include <hip/hip_bf16.h>

#define N_NODES 100000
#define N_EDGES 1250000
#define D_FEAT  64
#define NB      782            // buckets of 128 dst nodes: ceil(100000/128)
#define CAP     1792           // slots/bucket: mean 1600, sd ~40 -> +4.8 sigma
#define OVF_CAP 8192
#define EPB_I4  1024           // int4 edge-loads per build block (4096 edges)
#define N_I4    (N_EDGES / 4)  // 312500
#define NBLK_BUILD ((N_I4 + EPB_I4 - 1) / EPB_I4)   // 306

// ---- Pass 0: x (fp32) -> xh (bf16, RNE). 8 floats/thread. ----
__global__ __launch_bounds__(256) void to_bf16(
    const float* __restrict__ x, ushort* __restrict__ xh)
{
    int t = blockIdx.x * 256 + threadIdx.x;      // 800000 threads exactly
    const float4* x4 = (const float4*)x;
    float4 a = x4[2 * t];
    float4 b = x4[2 * t + 1];
    float f[8] = {a.x, a.y, a.z, a.w, b.x, b.y, b.z, b.w};
    uint h[8];
#pragma unroll
    for (int i = 0; i < 8; ++i) {
        uint u = __float_as_uint(f[i]);
        u += 0x7FFFu + ((u >> 16) & 1u);         // round to nearest even
        h[i] = u >> 16;
    }
    uint4 o;
    o.x = h[0] | (h[1] << 16);
    o.y = h[2] | (h[3] << 16);
    o.z = h[4] | (h[5] << 16);
    o.w = h[6] | (h[7] << 16);
    ((uint4*)xh)[t] = o;
}

// ---- Pass 1: bucket partition. LDS histogram + block-aggregated reservation. ----
// pairs word = (dstLocal7 << 17) | src17
__global__ __launch_bounds__(256) void build_buckets(
    const int* __restrict__ src, const int* __restrict__ dst,
    uint* __restrict__ fill, uint* __restrict__ pairs,
    uint* __restrict__ ovfCnt, int2* __restrict__ ovf)
{
    __shared__ uint cnt[NB];
    __shared__ uint base[NB];
    const int t = threadIdx.x;
    for (int i = t; i < NB; i += 256) cnt[i] = 0;
    __syncthreads();

    uint   pw[16];
    ushort pb[16];
    ushort pr[16];
    bool   vk[4];
    const int i40 = blockIdx.x * EPB_I4;
#pragma unroll
    for (int k = 0; k < 4; ++k) {
        int i4 = i40 + t + k * 256;
        vk[k] = (i4 < N_I4);
        if (vk[k]) {
            int4 d4 = ((const int4*)dst)[i4];
            int4 s4 = ((const int4*)src)[i4];
            int dd[4] = {d4.x, d4.y, d4.z, d4.w};
            int ss[4] = {s4.x, s4.y, s4.z, s4.w};
#pragma unroll
            for (int j = 0; j < 4; ++j) {
                uint b = ((uint)dd[j]) >> 7;
                uint r = atomicAdd(&cnt[b], 1u);
                pw[k * 4 + j] = ((((uint)dd[j]) & 127u) << 17) | (uint)ss[j];
                pb[k * 4 + j] = (ushort)b;
                pr[k * 4 + j] = (ushort)r;
            }
        }
    }
    __syncthreads();

    // one global atomic per nonzero bucket: reserve this block's range
    for (int i = t; i < NB; i += 256) {
        uint c = cnt[i];
        base[i] = c ? atomicAdd(&fill[i], c) : 0u;
    }
    __syncthreads();

#pragma unroll
    for (int j = 0; j < 16; ++j) {
        if (vk[j >> 2]) {
            uint b = pb[j];
            uint g = base[b] + pr[j];
            if (g < CAP) {
                pairs[(size_t)b * CAP + g] = pw[j];
            } else {
                uint o = atomicAdd(ovfCnt, 1u);
                if (o < OVF_CAP)
                    ovf[o] = make_int2((int)(pw[j] & 0x1FFFFu),
                                       (int)((b << 7) | (pw[j] >> 17)));
            }
        }
    }
}

// ---- Pass 2: per-bucket aggregate. 128 fp32 rows live in LDS (stride 65). ----
__global__ __launch_bounds__(256) void bucket_aggregate(
    const ushort* __restrict__ xh, const uint* __restrict__ pairs,
    const uint* __restrict__ fill, float* __restrict__ out)
{
    __shared__ float acc[128 * 65];   // 33,280 B; stride 65 spreads banks
    const int t = threadIdx.x;
    const int b = blockIdx.x;
    for (int i = t; i < 128 * 65; i += 256) acc[i] = 0.f;
    __syncthreads();

    const int n   = min((int)fill[b], CAP);
    const int g   = t >> 3;           // 32 edge-groups per block
    const int l8  = t & 7;            // 8 lanes x 16B cover a 128B bf16 row
    const size_t pbase = (size_t)b * CAP;
    const uint4* xrow = (const uint4*)xh;

    for (int e = g; e < n; e += 32) {
        uint p  = pairs[pbase + e];
        uint s  = p & 0x1FFFFu;
        uint dl = p >> 17;
        uint4 v = xrow[(size_t)s * 8 + l8];
        float* d = &acc[dl * 65 + l8 * 8];
        atomicAdd(d + 0, __uint_as_float((v.x & 0xFFFFu) << 16));
        atomicAdd(d + 1, __uint_as_float(v.x & 0xFFFF0000u));
        atomicAdd(d + 2, __uint_as_float((v.y & 0xFFFFu) << 16));
        atomicAdd(d + 3, __uint_as_float(v.y & 0xFFFF0000u));
        atomicAdd(d + 4, __uint_as_float((v.z & 0xFFFFu) << 16));
        atomicAdd(d + 5, __uint_as_float(v.z & 0xFFFF0000u));
        atomicAdd(d + 6, __uint_as_float((v.w & 0xFFFFu) << 16));
        atomicAdd(d + 7, __uint_as_float(v.w & 0xFFFF0000u));
    }
    __syncthreads();

    const int node0 = b * 128;
    const int nrows = min(128, N_NODES - node0);
    float4* out4 = (float4*)out;
    for (int i = t; i < nrows * 16; i += 256) {
        int row = i >> 4, q = i & 15;
        const float* a = &acc[row * 65 + q * 4];
        out4[(size_t)(node0 + row) * 16 + q] = make_float4(a[0], a[1], a[2], a[3]);
    }
}

// ---- Pass 3: add the (normally zero) overflow edges on top of out. ----
__global__ __launch_bounds__(256) void ovf_fixup(
    const float* __restrict__ x, const int2* __restrict__ ovf,
    const uint* __restrict__ ovfCnt, float* __restrict__ out)
{
    const int n = min((int)*ovfCnt, OVF_CAP);
    const int wave = (blockIdx.x * blockDim.x + threadIdx.x) >> 6;
    const int lane = threadIdx.x & 63;
    const int nwaves = (gridDim.x * blockDim.x) >> 6;
    for (int e = wave; e < n; e += nwaves) {
        int2 p = ovf[e];   // (src, dst)
        atomicAdd(&out[(size_t)p.y * D_FEAT + lane], x[(size_t)p.x * D_FEAT + lane]);
    }
}

extern "C" void kernel_launch(void* const* d_in, const int* in_sizes, int n_in,
                              void* d_out, int out_size, void* d_ws, size_t ws_size,
                              hipStream_t stream) {
    const float* x = (const float*)d_in[0];
    const int* edge_index = (const int*)d_in[1];    // [2, N_EDGES] flat int32
    const int* src = edge_index;
    const int* dst = edge_index + N_EDGES;
    float* out = (float*)d_out;

    // ws layout: xh[6.4M bf16 =12.8MB] | pairs[NB*CAP u32 =5.6MB] | fill[NB] | ovfCnt | pad | ovf[OVF_CAP int2]
    ushort* xh     = (ushort*)d_ws;
    uint*   pairs  = (uint*)(xh + (size_t)N_NODES * D_FEAT);
    uint*   fill   = pairs + (size_t)NB * CAP;
    uint*   ovfCnt = fill + NB;
    int2*   ovf    = (int2*)(ovfCnt + 2);           // 8B-aligned

    // zero fill + ovfCnt in one memset
    hipMemsetAsync(fill, 0, (NB + 2) * sizeof(uint), stream);

    to_bf16<<<(N_NODES * D_FEAT / 8) / 256, 256, 0, stream>>>(x, xh);   // 3125 blocks
    build_buckets<<<NBLK_BUILD, 256, 0, stream>>>(src, dst, fill, pairs, ovfCnt, ovf);
    bucket_aggregate<<<NB, 256, 0, stream>>>(xh, pairs, fill, out);
    ovf_fixup<<<16, 256, 0, stream>>>(x, ovf, ovfCnt, out);
}

// Round 7
// 147.204 us; speedup vs baseline: 4.2598x; 4.2598x over previous
//
#include <hip/hip_runtime.h>
#include <hip/hip_bf16.h>

#define N_NODES 100000
#define N_EDGES 1250000
#define D_FEAT  64
#define BKT_NODES 64
#define NB      1563           // ceil(100000/64) buckets of 64 dst nodes
#define CAP     1024           // slots/bucket: mean 800, sd ~28 -> +7.9 sigma
#define OVF_CAP 8192
#define EPB_I4  1024           // int4 edge-loads per build block (4096 edges)
#define N_I4    (N_EDGES / 4)  // 312500
#define NBLK_BUILD ((N_I4 + EPB_I4 - 1) / EPB_I4)   // 306

// ---- Pass 0: x (fp32) -> xh (bf16, RNE). 8 floats/thread. ----
__global__ __launch_bounds__(256) void to_bf16(
    const float* __restrict__ x, ushort* __restrict__ xh)
{
    int t = blockIdx.x * 256 + threadIdx.x;      // 800000 threads exactly
    const float4* x4 = (const float4*)x;
    float4 a = x4[2 * t];
    float4 b = x4[2 * t + 1];
    float f[8] = {a.x, a.y, a.z, a.w, b.x, b.y, b.z, b.w};
    uint h[8];
#pragma unroll
    for (int i = 0; i < 8; ++i) {
        uint u = __float_as_uint(f[i]);
        u += 0x7FFFu + ((u >> 16) & 1u);         // round to nearest even
        h[i] = u >> 16;
    }
    uint4 o;
    o.x = h[0] | (h[1] << 16);
    o.y = h[2] | (h[3] << 16);
    o.z = h[4] | (h[5] << 16);
    o.w = h[6] | (h[7] << 16);
    ((uint4*)xh)[t] = o;
}

// ---- Pass 1: bucket partition. LDS histogram + block-aggregated reservation. ----
// pairs word = (dstLocal6 << 17) | src17
__global__ __launch_bounds__(256) void build_buckets(
    const int* __restrict__ src, const int* __restrict__ dst,
    uint* __restrict__ fill, uint* __restrict__ pairs,
    uint* __restrict__ ovfCnt, int2* __restrict__ ovf)
{
    __shared__ uint cnt[NB];
    __shared__ uint base[NB];
    const int t = threadIdx.x;
    for (int i = t; i < NB; i += 256) cnt[i] = 0;
    __syncthreads();

    uint   pw[16];
    ushort pb[16];
    ushort pr[16];
    bool   vk[4];
    const int i40 = blockIdx.x * EPB_I4;
#pragma unroll
    for (int k = 0; k < 4; ++k) {
        int i4 = i40 + t + k * 256;
        vk[k] = (i4 < N_I4);
        if (vk[k]) {
            int4 d4 = ((const int4*)dst)[i4];
            int4 s4 = ((const int4*)src)[i4];
            int dd[4] = {d4.x, d4.y, d4.z, d4.w};
            int ss[4] = {s4.x, s4.y, s4.z, s4.w};
#pragma unroll
            for (int j = 0; j < 4; ++j) {
                uint b = ((uint)dd[j]) >> 6;
                uint r = atomicAdd(&cnt[b], 1u);
                pw[k * 4 + j] = ((((uint)dd[j]) & 63u) << 17) | (uint)ss[j];
                pb[k * 4 + j] = (ushort)b;
                pr[k * 4 + j] = (ushort)r;
            }
        }
    }
    __syncthreads();

    // one global atomic per nonzero bucket: reserve this block's range
    for (int i = t; i < NB; i += 256) {
        uint c = cnt[i];
        base[i] = c ? atomicAdd(&fill[i], c) : 0u;
    }
    __syncthreads();

#pragma unroll
    for (int j = 0; j < 16; ++j) {
        if (vk[j >> 2]) {
            uint b = pb[j];
            uint g = base[b] + pr[j];
            if (g < CAP) {
                pairs[(size_t)b * CAP + g] = pw[j];
            } else {
                uint o = atomicAdd(ovfCnt, 1u);
                if (o < OVF_CAP)
                    ovf[o] = make_int2((int)(pw[j] & 0x1FFFFu),
                                       (int)((b << 6) | (pw[j] >> 17)));
            }
        }
    }
}

// ---- Pass 2: per-bucket aggregate. Counting-sort in LDS, register accumulate. ----
__global__ __launch_bounds__(256) void bucket_aggregate(
    const ushort* __restrict__ xh, const uint* __restrict__ pairs,
    const uint* __restrict__ fill, float* __restrict__ out)
{
    __shared__ uint pw[CAP];
    __shared__ uint srt[CAP];
    __shared__ int  cnt[BKT_NODES];
    __shared__ int  scn[BKT_NODES];
    __shared__ int  basea[BKT_NODES];
    __shared__ int  pos[BKT_NODES];

    const int t = threadIdx.x;
    const int b = blockIdx.x;
    const int n = min((int)fill[b], CAP);

    if (t < BKT_NODES) cnt[t] = 0;
    __syncthreads();
    for (int i = t; i < n; i += 256) {
        uint w = pairs[(size_t)b * CAP + i];
        pw[i] = w;
        atomicAdd(&cnt[w >> 17], 1);
    }
    __syncthreads();

    if (t < BKT_NODES) scn[t] = cnt[t];
    __syncthreads();
    for (int off = 1; off < BKT_NODES; off <<= 1) {
        int v = (t < BKT_NODES && t >= off) ? scn[t - off] : 0;
        __syncthreads();
        if (t < BKT_NODES) scn[t] += v;
        __syncthreads();
    }
    if (t < BKT_NODES) { int e = scn[t] - cnt[t]; basea[t] = e; pos[t] = e; }
    __syncthreads();

    for (int i = t; i < n; i += 256) {
        uint w = pw[i];
        int r = atomicAdd(&pos[w >> 17], 1);
        srt[r] = w & 0x1FFFFu;
    }
    __syncthreads();

    const int wid  = t >> 6;       // wave 0..3
    const int lane = t & 63;
    const int sub  = lane >> 3;    // 8 subgroups: 8 edges in flight
    const int l8   = lane & 7;     // 16B chunk of the 128B bf16 row
    const uint4* __restrict__ xrow = (const uint4*)xh;

    for (int nl = wid; nl < BKT_NODES; nl += 4) {
        const int node  = b * BKT_NODES + nl;
        const int start = basea[nl];
        const int deg   = cnt[nl];

        float f[8];
#pragma unroll
        for (int j = 0; j < 8; ++j) f[j] = 0.f;

        int i = sub;
        for (; i + 8 < deg; i += 16) {         // 2-deep: 16 edges in flight
            uint s0 = srt[start + i];
            uint s1 = srt[start + i + 8];
            uint4 v0 = xrow[(size_t)s0 * 8 + l8];
            uint4 v1 = xrow[(size_t)s1 * 8 + l8];
            f[0] += __uint_as_float((v0.x & 0xFFFFu) << 16);
            f[1] += __uint_as_float(v0.x & 0xFFFF0000u);
            f[2] += __uint_as_float((v0.y & 0xFFFFu) << 16);
            f[3] += __uint_as_float(v0.y & 0xFFFF0000u);
            f[4] += __uint_as_float((v0.z & 0xFFFFu) << 16);
            f[5] += __uint_as_float(v0.z & 0xFFFF0000u);
            f[6] += __uint_as_float((v0.w & 0xFFFFu) << 16);
            f[7] += __uint_as_float(v0.w & 0xFFFF0000u);
            f[0] += __uint_as_float((v1.x & 0xFFFFu) << 16);
            f[1] += __uint_as_float(v1.x & 0xFFFF0000u);
            f[2] += __uint_as_float((v1.y & 0xFFFFu) << 16);
            f[3] += __uint_as_float(v1.y & 0xFFFF0000u);
            f[4] += __uint_as_float((v1.z & 0xFFFFu) << 16);
            f[5] += __uint_as_float(v1.z & 0xFFFF0000u);
            f[6] += __uint_as_float((v1.w & 0xFFFFu) << 16);
            f[7] += __uint_as_float(v1.w & 0xFFFF0000u);
        }
        if (i < deg) {
            uint s0 = srt[start + i];
            uint4 v0 = xrow[(size_t)s0 * 8 + l8];
            f[0] += __uint_as_float((v0.x & 0xFFFFu) << 16);
            f[1] += __uint_as_float(v0.x & 0xFFFF0000u);
            f[2] += __uint_as_float((v0.y & 0xFFFFu) << 16);
            f[3] += __uint_as_float(v0.y & 0xFFFF0000u);
            f[4] += __uint_as_float((v0.z & 0xFFFFu) << 16);
            f[5] += __uint_as_float(v0.z & 0xFFFF0000u);
            f[6] += __uint_as_float((v0.w & 0xFFFFu) << 16);
            f[7] += __uint_as_float(v0.w & 0xFFFF0000u);
        }

        // reduce the 8 subgroups: xor 8, 16, 32
#pragma unroll
        for (int j = 0; j < 8; ++j) {
            f[j] += __shfl_xor(f[j], 8, 64);
            f[j] += __shfl_xor(f[j], 16, 64);
            f[j] += __shfl_xor(f[j], 32, 64);
        }

        if (lane < 8 && node < N_NODES) {
            float4* out4 = (float4*)out;
            out4[(size_t)node * 16 + l8 * 2]     = make_float4(f[0], f[1], f[2], f[3]);
            out4[(size_t)node * 16 + l8 * 2 + 1] = make_float4(f[4], f[5], f[6], f[7]);
        }
    }
}

// ---- Pass 3: add the (normally zero) overflow edges on top of out. ----
__global__ __launch_bounds__(256) void ovf_fixup(
    const float* __restrict__ x, const int2* __restrict__ ovf,
    const uint* __restrict__ ovfCnt, float* __restrict__ out)
{
    const int n = min((int)*ovfCnt, OVF_CAP);
    const int wave = (blockIdx.x * blockDim.x + threadIdx.x) >> 6;
    const int lane = threadIdx.x & 63;
    const int nwaves = (gridDim.x * blockDim.x) >> 6;
    for (int e = wave; e < n; e += nwaves) {
        int2 p = ovf[e];   // (src, dst)
        atomicAdd(&out[(size_t)p.y * D_FEAT + lane], x[(size_t)p.x * D_FEAT + lane]);
    }
}

extern "C" void kernel_launch(void* const* d_in, const int* in_sizes, int n_in,
                              void* d_out, int out_size, void* d_ws, size_t ws_size,
                              hipStream_t stream) {
    const float* x = (const float*)d_in[0];
    const int* edge_index = (const int*)d_in[1];    // [2, N_EDGES] flat int32
    const int* src = edge_index;
    const int* dst = edge_index + N_EDGES;
    float* out = (float*)d_out;

    // ws: xh[6.4M bf16 =12.8MB] | pairs[NB*CAP u32 =6.4MB] | fill[NB] | ovfCnt | pad | ovf[OVF_CAP int2]
    ushort* xh     = (ushort*)d_ws;
    uint*   pairs  = (uint*)(xh + (size_t)N_NODES * D_FEAT);
    uint*   fill   = pairs + (size_t)NB * CAP;
    uint*   ovfCnt = fill + NB;
    int2*   ovf    = (int2*)(fill + NB + 3);        // 8B-aligned (NB odd)

    hipMemsetAsync(fill, 0, (NB + 3) * sizeof(uint), stream);

    to_bf16<<<(N_NODES * D_FEAT / 8) / 256, 256, 0, stream>>>(x, xh);   // 3125 blocks
    build_buckets<<<NBLK_BUILD, 256, 0, stream>>>(src, dst, fill, pairs, ovfCnt, ovf);
    bucket_aggregate<<<NB, 256, 0, stream>>>(xh, pairs, fill, out);
    ovf_fixup<<<16, 256, 0, stream>>>(x, ovf, ovfCnt, out);
}